// Round 7
// baseline (135.853 us; speedup 1.0000x reference)
//
#include <hip/hip_runtime.h>
#include <hip/hip_bf16.h>
#include <math.h>

#define D    64
#define F3   192
#define NPB  256          // nodes per bucket (local dst = 8 bits)
#define LBITS 8
#define SBITS 17          // src id fits in 17 bits (N=100000 < 131072)
#define NBLK 256          // edge blocks for binning passes
#define SCAN_CHUNK 2048   // 256 threads * 8 elements
#define FPAD 200          // padded LDS feats row (ushorts): 400B stride

using bf16x8 = __attribute__((ext_vector_type(8))) short;
using f32x4  = __attribute__((ext_vector_type(4))) float;

__device__ __forceinline__ ushort f2bf(float f) {
    __hip_bfloat16 h = __float2bfloat16(f);
    return *reinterpret_cast<ushort*>(&h);
}
__device__ __forceinline__ float bf2f(ushort u) {
    unsigned v = ((unsigned)u) << 16;
    return __uint_as_float(v);
}

// ---------------- Pre-casts ----------------

__global__ __launch_bounds__(256) void k_wcast(
    const float* __restrict__ W, ushort* __restrict__ Wb, int n)
{
    for (int i = threadIdx.x; i < n; i += 256) Wb[i] = f2bf(W[i]);
}

__global__ __launch_bounds__(256) void k_xcast(
    const float* __restrict__ x, ushort* __restrict__ xb, int n4)
{
    int i = blockIdx.x * 256 + threadIdx.x;
    if (i >= n4) return;
    float4 v = *reinterpret_cast<const float4*>(x + (size_t)i * 4);
    ushort4 u = { f2bf(v.x), f2bf(v.y), f2bf(v.z), f2bf(v.w) };
    *reinterpret_cast<ushort4*>(xb + (size_t)i * 4) = u;
}

// ---------------- Phase A: bucketed CSR construction ----------------

__global__ __launch_bounds__(256) void k_bin_hist(
    const int* __restrict__ dstv, unsigned* __restrict__ bcntT,
    int E, int EPB, int NB)
{
    __shared__ unsigned h[512];
    for (int i = threadIdx.x; i < NB; i += 256) h[i] = 0;
    __syncthreads();
    int lo = blockIdx.x * EPB, hi = min(E, lo + EPB);
    for (int e = lo + threadIdx.x; e < hi; e += 256)
        atomicAdd(&h[((unsigned)dstv[e]) >> LBITS], 1u);
    __syncthreads();
    for (int i = threadIdx.x; i < NB; i += 256)
        bcntT[(size_t)i * NBLK + blockIdx.x] = h[i];
}

__global__ __launch_bounds__(256) void k_chunk_scan(
    const unsigned* __restrict__ cnt, unsigned* __restrict__ offs,
    unsigned* __restrict__ partials, int N)
{
    __shared__ unsigned ts[256];
    int t = threadIdx.x;
    int ebase = blockIdx.x * SCAN_CHUNK + t * 8;
    unsigned v[8];
    unsigned s = 0;
    #pragma unroll
    for (int j = 0; j < 8; ++j) {
        unsigned c = (ebase + j < N) ? cnt[ebase + j] : 0u;
        v[j] = s; s += c;
    }
    ts[t] = s;
    __syncthreads();
    #pragma unroll
    for (int off = 1; off < 256; off <<= 1) {
        unsigned add = (t >= off) ? ts[t - off] : 0u;
        __syncthreads();
        ts[t] += add;
        __syncthreads();
    }
    unsigned tb = (t > 0) ? ts[t - 1] : 0u;
    #pragma unroll
    for (int j = 0; j < 8; ++j)
        if (ebase + j < N) offs[ebase + j] = tb + v[j];
    if (t == 255) partials[blockIdx.x] = ts[255];
}

__global__ void k_scan_partials(unsigned* partials, int n)
{
    if (blockIdx.x == 0 && threadIdx.x == 0) {
        unsigned s = 0;
        for (int i = 0; i < n; ++i) { unsigned c = partials[i]; partials[i] = s; s += c; }
    }
}

__global__ __launch_bounds__(256) void k_add_base(
    unsigned* __restrict__ offs, const unsigned* __restrict__ partials, int N)
{
    int i = blockIdx.x * 256 + threadIdx.x;
    if (i < N) offs[i] += partials[i / SCAN_CHUNK];
}

__global__ __launch_bounds__(256) void k_bin_scatter(
    const int* __restrict__ srcv, const int* __restrict__ dstv,
    const unsigned* __restrict__ bbaseT, unsigned* __restrict__ binned,
    int E, int EPB, int NB)
{
    __shared__ unsigned cur[512];
    for (int i = threadIdx.x; i < NB; i += 256)
        cur[i] = bbaseT[(size_t)i * NBLK + blockIdx.x];
    __syncthreads();
    int lo = blockIdx.x * EPB, hi = min(E, lo + EPB);
    for (int e = lo + threadIdx.x; e < hi; e += 256) {
        unsigned d = (unsigned)dstv[e];
        unsigned s = (unsigned)srcv[e];
        unsigned p = atomicAdd(&cur[d >> LBITS], 1u);
        binned[p] = ((d & (NPB - 1u)) << SBITS) | s;
    }
}

__global__ __launch_bounds__(256) void k_bucket_csr(
    const unsigned* __restrict__ binned, const unsigned* __restrict__ bbaseT,
    unsigned* __restrict__ offs, unsigned* __restrict__ cnt,
    unsigned* __restrict__ ssrc, int E, int NB, int N)
{
    __shared__ unsigned c[256];
    __shared__ unsigned ts[256];
    int k = blockIdx.x;
    int t = threadIdx.x;
    unsigned bstart = bbaseT[(size_t)k * NBLK];
    unsigned bend   = (k + 1 < NB) ? bbaseT[(size_t)(k + 1) * NBLK] : (unsigned)E;

    c[t] = 0;
    __syncthreads();
    for (unsigned e = bstart + t; e < bend; e += 256)
        atomicAdd(&c[binned[e] >> SBITS], 1u);
    __syncthreads();

    unsigned myc = c[t];
    ts[t] = myc;
    __syncthreads();
    #pragma unroll
    for (int off = 1; off < 256; off <<= 1) {
        unsigned add = (t >= off) ? ts[t - off] : 0u;
        __syncthreads();
        ts[t] += add;
        __syncthreads();
    }
    unsigned excl = t ? ts[t - 1] : 0u;

    int gn = k * NPB + t;
    if (gn < N) { offs[gn] = bstart + excl; cnt[gn] = myc; }

    c[t] = excl;
    __syncthreads();
    for (unsigned e = bstart + t; e < bend; e += 256) {
        unsigned u  = binned[e];
        unsigned ld = u >> SBITS;
        unsigned r  = atomicAdd(&c[ld], 1u);
        ssrc[bstart + r] = u & ((1u << SBITS) - 1u);
    }
}

// ---------------- Phase B: fused gather + MFMA MLP ----------------
// Block = 256 threads = 4 waves, grid-strides over 16-node tiles.
// Gather: wave = node. 4 lane-groups x 16 lanes; edge list preloaded into
// registers (one coalesced load per 64 edges), broadcast via __shfl.
// CORRECTNESS RULE (round-6 bug): every __shfl executes under a
// wave-UNIFORM condition (i+8<=m / i+4<=m), so all 64 lanes are active and
// all source lanes hold valid slist. The last <4 edges use DIRECT ssrc
// loads — __shfl under group-divergent predicates reads inactive lanes
// (ds_bpermute -> undefined/0) and silently corrupts ~1-2% of nodes.
__global__ __launch_bounds__(256) void k_fused(
    const ushort*   __restrict__ xb,      // [N][64] bf16
    const unsigned* __restrict__ ssrc,
    const unsigned* __restrict__ offs,
    const unsigned* __restrict__ cnt,
    const ushort*   __restrict__ Wb,      // [64][192] bf16
    const float*    __restrict__ bias,    // [64]
    float*          __restrict__ out,     // [N][64]
    int N)
{
    __shared__ ushort fl[16][FPAD];

    int tid  = threadIdx.x;
    int lane = tid & 63;
    int wv   = tid >> 6;
    int g    = lane >> 4;            // edge group 0..3
    int c4   = (lane & 15) << 2;     // channel base 0,4,...,60
    int l16  = lane & 15;
    int kb   = (lane >> 4) << 3;     // MFMA k sub-offset

    int col = (wv << 4) + l16;
    const ushort* wp = Wb + (size_t)col * F3 + kb;
    bf16x8 bfr[6];
    #pragma unroll
    for (int ks = 0; ks < 6; ++ks)
        bfr[ks] = *reinterpret_cast<const bf16x8*>(wp + ks * 32);
    float bo = bias[col];

    int ntiles = N >> 4;             // N divisible by 16
    for (int t = blockIdx.x; t < ntiles; t += gridDim.x) {
        int n0 = t << 4;

        // ---- gather 4 nodes per wave ----
        #pragma unroll 1
        for (int q = 0; q < 4; ++q) {
            int nd = (wv << 2) + q;
            int n  = n0 + nd;
            unsigned st = offs[n];
            unsigned dg = cnt[n];

            float4 sv = make_float4(0.f, 0.f, 0.f, 0.f);
            float4 mv = make_float4(-INFINITY, -INFINITY, -INFINITY, -INFINITY);

            for (unsigned base = 0; base < dg; base += 64) {
                unsigned m = min(64u, dg - base);
                unsigned slist = ((unsigned)lane < m) ? ssrc[st + base + lane] : 0u;
                unsigned i = 0;
                // 8 edges/iter — condition uniform, all lanes active,
                // shfl sources i+g..i+7 <= m-1 all hold valid slist.
                for (; i + 8 <= m; i += 8) {
                    unsigned s0 = (unsigned)__shfl((int)slist, (int)(i + g));
                    unsigned s1 = (unsigned)__shfl((int)slist, (int)(i + 4 + g));
                    ushort4 u0 = *reinterpret_cast<const ushort4*>(xb + (size_t)s0 * D + c4);
                    ushort4 u1 = *reinterpret_cast<const ushort4*>(xb + (size_t)s1 * D + c4);
                    float a0 = bf2f(u0.x), a1 = bf2f(u0.y), a2 = bf2f(u0.z), a3 = bf2f(u0.w);
                    float b0 = bf2f(u1.x), b1 = bf2f(u1.y), b2 = bf2f(u1.z), b3 = bf2f(u1.w);
                    sv.x += a0 + b0; sv.y += a1 + b1; sv.z += a2 + b2; sv.w += a3 + b3;
                    mv.x = fmaxf(mv.x, fmaxf(a0, b0)); mv.y = fmaxf(mv.y, fmaxf(a1, b1));
                    mv.z = fmaxf(mv.z, fmaxf(a2, b2)); mv.w = fmaxf(mv.w, fmaxf(a3, b3));
                }
                // 4 edges — condition still uniform (i, m wave-uniform).
                if (i + 4 <= m) {
                    unsigned s0 = (unsigned)__shfl((int)slist, (int)(i + g));
                    ushort4 u0 = *reinterpret_cast<const ushort4*>(xb + (size_t)s0 * D + c4);
                    float a0 = bf2f(u0.x), a1 = bf2f(u0.y), a2 = bf2f(u0.z), a3 = bf2f(u0.w);
                    sv.x += a0; sv.y += a1; sv.z += a2; sv.w += a3;
                    mv.x = fmaxf(mv.x, a0); mv.y = fmaxf(mv.y, a1);
                    mv.z = fmaxf(mv.z, a2); mv.w = fmaxf(mv.w, a3);
                    i += 4;
                }
                // <4 edges — DIVERGENT: direct load, no cross-lane ops.
                if (i + (unsigned)g < m) {
                    unsigned s0 = ssrc[st + base + i + (unsigned)g];
                    ushort4 u0 = *reinterpret_cast<const ushort4*>(xb + (size_t)s0 * D + c4);
                    float a0 = bf2f(u0.x), a1 = bf2f(u0.y), a2 = bf2f(u0.z), a3 = bf2f(u0.w);
                    sv.x += a0; sv.y += a1; sv.z += a2; sv.w += a3;
                    mv.x = fmaxf(mv.x, a0); mv.y = fmaxf(mv.y, a1);
                    mv.z = fmaxf(mv.z, a2); mv.w = fmaxf(mv.w, a3);
                }
            }

            #pragma unroll
            for (int off = 16; off <= 32; off <<= 1) {
                sv.x += __shfl_xor(sv.x, off); sv.y += __shfl_xor(sv.y, off);
                sv.z += __shfl_xor(sv.z, off); sv.w += __shfl_xor(sv.w, off);
                mv.x = fmaxf(mv.x, __shfl_xor(mv.x, off));
                mv.y = fmaxf(mv.y, __shfl_xor(mv.y, off));
                mv.z = fmaxf(mv.z, __shfl_xor(mv.z, off));
                mv.w = fmaxf(mv.w, __shfl_xor(mv.w, off));
            }

            float inv = dg ? 1.0f / (float)dg : 0.0f;
            if (g == 0) {
                ushort4 u = { f2bf(sv.x), f2bf(sv.y), f2bf(sv.z), f2bf(sv.w) };
                *reinterpret_cast<ushort4*>(&fl[nd][c4]) = u;
            } else if (g == 1) {
                ushort4 u = { f2bf(sv.x * inv), f2bf(sv.y * inv),
                              f2bf(sv.z * inv), f2bf(sv.w * inv) };
                *reinterpret_cast<ushort4*>(&fl[nd][D + c4]) = u;
            } else if (g == 2) {
                float4 m4 = mv;
                if (dg == 0) m4 = make_float4(0.f, 0.f, 0.f, 0.f);
                ushort4 u = { f2bf(m4.x), f2bf(m4.y), f2bf(m4.z), f2bf(m4.w) };
                *reinterpret_cast<ushort4*>(&fl[nd][2 * D + c4]) = u;
            }
        }
        __syncthreads();

        // ---- MFMA: out[tile] = feats_lds @ Wb^T + b ----
        bf16x8 afr[6];
        #pragma unroll
        for (int ks = 0; ks < 6; ++ks)
            afr[ks] = *reinterpret_cast<const bf16x8*>(&fl[l16][kb + ks * 32]);

        f32x4 acc = { bo, bo, bo, bo };
        #pragma unroll
        for (int ks = 0; ks < 6; ++ks)
            acc = __builtin_amdgcn_mfma_f32_16x16x32_bf16(afr[ks], bfr[ks], acc, 0, 0, 0);

        int rbase = n0 + ((lane >> 4) << 2);
        #pragma unroll
        for (int r = 0; r < 4; ++r)
            out[(size_t)(rbase + r) * D + col] = acc[r];
        __syncthreads();
    }
}

extern "C" void kernel_launch(void* const* d_in, const int* in_sizes, int n_in,
                              void* d_out, int out_size, void* d_ws, size_t ws_size,
                              hipStream_t stream)
{
    const float* x  = (const float*)d_in[0];
    const int*   ei = (const int*)d_in[1];
    const float* W  = (const float*)d_in[2];
    const float* b  = (const float*)d_in[3];
    float* out = (float*)d_out;

    int N = in_sizes[0] / D;
    int E = in_sizes[1] / 2;
    const int* srcv = ei;
    const int* dstv = ei + E;

    int NB  = (N + NPB - 1) / NPB;          // 391 buckets
    int EPB = (E + NBLK - 1) / NBLK;
    int M   = NB * NBLK;

    unsigned* bcntT    = (unsigned*)d_ws;   // [M]
    unsigned* bbaseT   = bcntT + M;         // [M]
    unsigned* partials = bbaseT + M;        // [64]
    unsigned* offs     = partials + 64;     // [N]
    unsigned* cnt      = offs + N;          // [N]
    unsigned* ssrc     = cnt + N;           // [E]
    unsigned* binned   = ssrc + E;          // [E]
    ushort*   xb       = (ushort*)(binned + E);   // [N*64] bf16
    ushort*   Wb       = xb + (size_t)N * D;      // [64*192] bf16

    int nChunksM = (M + SCAN_CHUNK - 1) / SCAN_CHUNK;

    k_wcast<<<1, 256, 0, stream>>>(W, Wb, D * F3);
    k_xcast<<<(N * D / 4 + 255) / 256, 256, 0, stream>>>(x, xb, N * D / 4);

    k_bin_hist<<<NBLK, 256, 0, stream>>>(dstv, bcntT, E, EPB, NB);
    k_chunk_scan<<<nChunksM, 256, 0, stream>>>(bcntT, bbaseT, partials, M);
    k_scan_partials<<<1, 64, 0, stream>>>(partials, nChunksM);
    k_add_base<<<(M + 255) / 256, 256, 0, stream>>>(bbaseT, partials, M);
    k_bin_scatter<<<NBLK, 256, 0, stream>>>(srcv, dstv, bbaseT, binned, E, EPB, NB);
    k_bucket_csr<<<NB, 256, 0, stream>>>(binned, bbaseT, offs, cnt, ssrc, E, NB, N);

    k_fused<<<2048, 256, 0, stream>>>(xb, ssrc, offs, cnt, Wb, b, out, N);
}